// Round 4
// baseline (114.444 us; speedup 1.0000x reference)
//
#include <hip/hip_runtime.h>
#include <hip/hip_bf16.h>

#define NH 8
#define HID 64
#define NPAIRS (16 * 256 * 256)
#define BLOCK 256
#define GPW 8      // groups of 16 pairs per wave
#define LSTR 68    // f32 stride per pair-row in LDS transpose buffer (16B-aligned rows, 2-way max write conflict)

typedef __attribute__((ext_vector_type(8))) short bf16x8;  // 8 bf16 = 4 VGPRs (guide-verified frag type)
typedef __attribute__((ext_vector_type(4))) float f32x4;

union F8 { bf16x8 v; unsigned u[4]; uint4 q4; };

// f32 pair -> packed bf16 dword, round-to-nearest-even
__device__ __host__ inline unsigned bfpk(float a, float b) {
    unsigned ua = __float_as_uint(a); ua += 0x7fffu + ((ua >> 16) & 1u);
    unsigned ub = __float_as_uint(b); ub += 0x7fffu + ((ub >> 16) & 1u);
    return (ua >> 16) | (ub & 0xffff0000u);
}

// Workspace layout (bytes):
//   0     : B1 frags  [nb 0..3][lane 0..63] x 16B   (W1 in B-layout, K pad 12->32)  4096
//   4096  : B2 frags  [kc 0..1][lane 0..63] x 16B   (W2 in B-layout, N pad 8->16)   2048
//   6144  : b1v       [nb 0..3][lane 0..63] f32     (b1[nb*16 + (lane&15)])         1024
//   7168  : b2v       [lane 0..63] f32              (lane&15<8 ? b2[lane&15] : 0)    256
__global__ void pack_weights(const float* __restrict__ W1, const float* __restrict__ b1,
                             const float* __restrict__ W2, const float* __restrict__ b2,
                             unsigned char* __restrict__ ws) {
    int l = threadIdx.x;            // 0..63
    int n = l & 15, q = l >> 4;
    unsigned* B1 = (unsigned*)ws;
    unsigned* B2 = (unsigned*)(ws + 4096);
    float* b1v = (float*)(ws + 6144);
    float* b2v = (float*)(ws + 7168);
    // B-layout for 16x16x32: lane holds B[k = q*8 + j][n = lane&15], j = 0..7
    for (int nb = 0; nb < 4; ++nb) {
        int h = nb * 16 + n;
        for (int j2 = 0; j2 < 4; ++j2) {
            int k0 = q * 8 + 2 * j2;
            float v0 = (k0 < 12) ? W1[k0 * HID + h] : 0.f;
            float v1 = (k0 + 1 < 12) ? W1[(k0 + 1) * HID + h] : 0.f;
            B1[(nb * 64 + l) * 4 + j2] = bfpk(v0, v1);
        }
        b1v[nb * 64 + l] = b1[h];
    }
    for (int kc = 0; kc < 2; ++kc)
        for (int j2 = 0; j2 < 4; ++j2) {
            int k0 = kc * 32 + q * 8 + 2 * j2;
            float v0 = (n < NH) ? W2[k0 * NH + n] : 0.f;
            float v1 = (n < NH) ? W2[(k0 + 1) * NH + n] : 0.f;
            B2[(kc * 64 + l) * 4 + j2] = bfpk(v0, v1);
        }
    b2v[l] = (n < NH) ? b2[n] : 0.f;
}

__global__ __launch_bounds__(BLOCK) void relfeat_mfma(
    const float* __restrict__ ff, const unsigned char* __restrict__ ws,
    float* __restrict__ out)
{
    __shared__ float lds[4][16 * LSTR];   // per-wave private transpose buffers (no barriers needed)
    const int tid = threadIdx.x;
    const int w = tid >> 6, l = tid & 63;
    const int n = l & 15, q = l >> 4;
    float* my = lds[w];

    // Per-lane weight fragments (cached global loads, once per thread)
    F8 B1[4]; F8 B2[2];
    const uint4* B1p = (const uint4*)ws;
    const uint4* B2p = (const uint4*)(ws + 4096);
    #pragma unroll
    for (int nb = 0; nb < 4; ++nb) B1[nb].q4 = B1p[nb * 64 + l];
    #pragma unroll
    for (int kc = 0; kc < 2; ++kc) B2[kc].q4 = B2p[kc * 64 + l];
    float b1v[4];
    #pragma unroll
    for (int nb = 0; nb < 4; ++nb) b1v[nb] = ((const float*)(ws + 6144))[nb * 64 + l];
    const float b2v = ((const float*)(ws + 7168))[l];

    const int wave_base = (blockIdx.x * 4 + w) * (GPW * 16);

    for (int g = 0; g < GPW; ++g) {
        const int pbase = wave_base + g * 16;

        // ---- A1 fragment: A[m = pair = lane&15][k = feat = q*8 + j] ----
        F8 a1; a1.u[0] = a1.u[1] = a1.u[2] = a1.u[3] = 0u;
        if (q < 2) {
            float4 v = ((const float4*)ff)[pbase + n];
            float rx = v.x, ry = v.y, rvx = v.z, rvy = v.w;
            float dist_sq = rx * rx + ry * ry;
            float dist = sqrtf(dist_sq + 1e-6f);
            float speed_sq = rvx * rvx + rvy * rvy;
            float dot_vp = rvx * rx + rvy * ry;
            float invd = __builtin_amdgcn_rcpf(dist + 1e-6f);
            if (q == 0) {   // feats 0..7: rx,ry,rvx,rvy,dist,inv_dist,rel_speed,closing
                float inv_dist = __builtin_amdgcn_rcpf(dist + 0.1f);
                float rel_speed = sqrtf(speed_sq + 1e-6f);
                float closing = dot_vp * invd;
                a1.u[0] = bfpk(rx, ry);
                a1.u[1] = bfpk(rvx, rvy);
                a1.u[2] = bfpk(dist, inv_dist);
                a1.u[3] = bfpk(rel_speed, closing);
            } else {        // feats 8..11: dir_x,dir_y,ttca,dot_vp (+4 zero pad)
                float dir_x = rx * invd, dir_y = ry * invd;
                float z = -dot_vp * __builtin_amdgcn_rcpf(speed_sq + 1e-6f);
                float ez = __expf(2.f * z);                       // tanh(z) = 1 - 2/(e^{2z}+1)
                float ttca = 1.f - 2.f * __builtin_amdgcn_rcpf(ez + 1.f);
                a1.u[0] = bfpk(dir_x, dir_y);
                a1.u[1] = bfpk(ttca, dot_vp);
            }
        }

        // ---- GEMM1 (16 pairs x 64 hidden), + b1, silu, write to LDS[pair][hid] ----
        #pragma unroll
        for (int nb = 0; nb < 4; ++nb) {
            f32x4 d1 = {0.f, 0.f, 0.f, 0.f};
            d1 = __builtin_amdgcn_mfma_f32_16x16x32_bf16(a1.v, B1[nb].v, d1, 0, 0, 0);
            // C/D layout: col(hid) = nb*16 + (lane&15), row(pair) = q*4 + reg
            #pragma unroll
            for (int r = 0; r < 4; ++r) {
                float x = d1[r] + b1v[nb];
                float s = x * __builtin_amdgcn_rcpf(1.f + __expf(-x));   // silu
                my[(q * 4 + r) * LSTR + nb * 16 + n] = s;
            }
        }

        // ---- transpose read -> A2[m = pair = lane&15][k = hid = kc*32 + q*8 + j]; GEMM2 ----
        f32x4 d2 = {b2v, b2v, b2v, b2v};
        #pragma unroll
        for (int kc = 0; kc < 2; ++kc) {
            const float* rp = &my[n * LSTR + kc * 32 + q * 8];
            float4 lo = *(const float4*)rp;
            float4 hi = *(const float4*)(rp + 4);
            F8 a2;
            a2.u[0] = bfpk(lo.x, lo.y); a2.u[1] = bfpk(lo.z, lo.w);
            a2.u[2] = bfpk(hi.x, hi.y); a2.u[3] = bfpk(hi.z, hi.w);
            d2 = __builtin_amdgcn_mfma_f32_16x16x32_bf16(a2.v, B2[kc].v, d2, 0, 0, 0);
        }

        // ---- store: D2 row = pair q*4+reg (4 consecutive), col = o = lane&15 -> dwordx4 ----
        if (n < NH) {
            int p0 = pbase + q * 4;
            int b = p0 >> 16, lo16 = p0 & 65535;
            float4 st; st.x = d2[0]; st.y = d2[1]; st.z = d2[2]; st.w = d2[3];
            *(float4*)(out + (size_t)b * (NH * 65536) + (size_t)n * 65536 + lo16) = st;
        }
    }
}

extern "C" void kernel_launch(void* const* d_in, const int* in_sizes, int n_in,
                              void* d_out, int out_size, void* d_ws, size_t ws_size,
                              hipStream_t stream) {
    const float* ff = (const float*)d_in[0];
    const float* W1 = (const float*)d_in[1];
    const float* b1 = (const float*)d_in[2];
    const float* W2 = (const float*)d_in[3];
    const float* b2 = (const float*)d_in[4];
    float* out = (float*)d_out;
    unsigned char* ws = (unsigned char*)d_ws;   // 7424 bytes used

    pack_weights<<<1, 64, 0, stream>>>(W1, b1, W2, b2, ws);
    const int grid = NPAIRS / (16 * GPW * 4);   // 2048 blocks (4 waves x 8 groups x 16 pairs)
    relfeat_mfma<<<grid, BLOCK, 0, stream>>>(ff, ws, out);
}

// Round 5
// 104.834 us; speedup vs baseline: 1.0917x; 1.0917x over previous
//
#include <hip/hip_runtime.h>

#define NH 8
#define HID 64
#define NPAIRS (16 * 256 * 256)
#define BLOCK 256
#define GPW 4      // groups of 32 pairs per wave
#define LSTR 68    // f32 row stride in LDS transpose buffer (16B-aligned, <=2-way banks)

typedef __attribute__((ext_vector_type(8))) short bf16x8;
typedef __attribute__((ext_vector_type(4))) float f32x4;
typedef __attribute__((ext_vector_type(16))) float f32x16;

union F8 { bf16x8 v; unsigned u[4]; uint4 q4; };

// f32 pair -> packed bf16 dword (RNE)
__device__ __host__ inline unsigned bfpk(float a, float b) {
    unsigned ua = __float_as_uint(a); ua += 0x7fffu + ((ua >> 16) & 1u);
    unsigned ub = __float_as_uint(b); ub += 0x7fffu + ((ub >> 16) & 1u);
    return (ua >> 16) | (ub & 0xffff0000u);
}

// ws layout (bytes):
//   0    : B1 frags [m=0,1][lane] x16B  — W1 in 32x32x16 B-layout, hid half m   2048
//   2048 : B2 frags [kc=0,1][lane] x16B — W2 in 16x16x32 B-layout (R4-verified) 2048
//   4096 : b1v [m=0,1][lane] f32        — b1[m*32 + (lane&31)]                   512
//   4608 : b2v [lane] f32               — lane&15<8 ? b2[lane&15] : 0            256
__global__ void pack_weights(const float* __restrict__ W1, const float* __restrict__ b1,
                             const float* __restrict__ W2, const float* __restrict__ b2,
                             unsigned char* __restrict__ ws) {
    int l = threadIdx.x;                 // 0..63
    int n32 = l & 31, q2 = l >> 5;
    int n16 = l & 15, q4 = l >> 4;
    unsigned* B1 = (unsigned*)ws;
    unsigned* B2 = (unsigned*)(ws + 2048);
    float* b1v = (float*)(ws + 4096);
    float* b2v = (float*)(ws + 4608);
    // 32x32x16 B-layout: lane holds B[k = q2*8 + j][n = l&31], j = 0..7
    for (int m = 0; m < 2; ++m) {
        int h = m * 32 + n32;
        for (int j2 = 0; j2 < 4; ++j2) {
            int k0 = q2 * 8 + 2 * j2;
            float v0 = (k0 < 12) ? W1[k0 * HID + h] : 0.f;
            float v1 = (k0 + 1 < 12) ? W1[(k0 + 1) * HID + h] : 0.f;
            B1[(m * 64 + l) * 4 + j2] = bfpk(v0, v1);
        }
        b1v[m * 64 + l] = b1[h];
    }
    // 16x16x32 B-layout (unchanged from R4): lane holds B[k = kc*32 + q4*8 + j][n16]
    for (int kc = 0; kc < 2; ++kc)
        for (int j2 = 0; j2 < 4; ++j2) {
            int k0 = kc * 32 + q4 * 8 + 2 * j2;
            float v0 = (n16 < NH) ? W2[k0 * NH + n16] : 0.f;
            float v1 = (n16 < NH) ? W2[(k0 + 1) * NH + n16] : 0.f;
            B2[(kc * 64 + l) * 4 + j2] = bfpk(v0, v1);
        }
    b2v[l] = (n16 < NH) ? b2[n16] : 0.f;
}

__global__ __launch_bounds__(BLOCK) void relfeat_mfma2(
    const float* __restrict__ ff, const unsigned char* __restrict__ ws,
    float* __restrict__ out)
{
    __shared__ float lds[4][32 * LSTR];   // per-wave private buffers, no barriers
    const int tid = threadIdx.x;
    const int w = tid >> 6, l = tid & 63;
    const int n32 = l & 31, q2 = l >> 5;
    const int n16 = l & 15, q4 = l >> 4;
    float* my = lds[w];

    F8 B1f[2], B2f[2];
    #pragma unroll
    for (int m = 0; m < 2; ++m)  B1f[m].q4 = ((const uint4*)ws)[m * 64 + l];
    #pragma unroll
    for (int kc = 0; kc < 2; ++kc) B2f[kc].q4 = ((const uint4*)(ws + 2048))[kc * 64 + l];
    float b1s[2];
    b1s[0] = ((const float*)(ws + 4096))[l];
    b1s[1] = ((const float*)(ws + 4096))[64 + l];
    const float b2s = ((const float*)(ws + 4608))[l];

    // Loop-invariant bias accumulators (hoisted by RA; b1 add folded into MFMA C)
    f32x16 cbias[2];
    #pragma unroll
    for (int m = 0; m < 2; ++m)
        #pragma unroll
        for (int r = 0; r < 16; ++r) cbias[m][r] = b1s[m];

    const int wave_base = (blockIdx.x * 4 + w) * (GPW * 32);

    for (int g = 0; g < GPW; ++g) {
        const int pbase = wave_base + g * 32;

        // ---- features: every lane computes pair (l&31); halves pack different k ----
        float4 v = ((const float4*)ff)[pbase + n32];
        float rx = v.x, ry = v.y, rvx = v.z, rvy = v.w;
        float dist_sq = rx * rx + ry * ry;
        float dist = sqrtf(dist_sq + 1e-6f);
        float speed_sq = rvx * rvx + rvy * rvy;
        float dot_vp = rvx * rx + rvy * ry;
        float invd = __builtin_amdgcn_rcpf(dist + 1e-6f);
        float inv_dist = __builtin_amdgcn_rcpf(dist + 0.1f);
        float rel_speed = sqrtf(speed_sq + 1e-6f);
        float closing = dot_vp * invd;
        float dir_x = rx * invd, dir_y = ry * invd;
        float z = -dot_vp * __builtin_amdgcn_rcpf(speed_sq + 1e-6f);
        float ez = __expf(2.f * z);
        float ttca = 1.f - 2.f * __builtin_amdgcn_rcpf(ez + 1.f);   // tanh(z)

        // A1 (32x32x16): A[m = pair = l&31][k = q2*8 + j]; feats 0..11, pad to 16
        F8 a1;
        a1.u[0] = (q2 == 0) ? bfpk(rx, ry)          : bfpk(dir_x, dir_y);
        a1.u[1] = (q2 == 0) ? bfpk(rvx, rvy)        : bfpk(ttca, dot_vp);
        a1.u[2] = (q2 == 0) ? bfpk(dist, inv_dist)  : 0u;
        a1.u[3] = (q2 == 0) ? bfpk(rel_speed, closing) : 0u;

        // ---- GEMM1: 2x mfma 32x32x16 (hid halves), silu, LDS [pair][hid] ----
        #pragma unroll
        for (int m = 0; m < 2; ++m) {
            f32x16 d1 = __builtin_amdgcn_mfma_f32_32x32x16_bf16(a1.v, B1f[m].v, cbias[m], 0, 0, 0);
            // C/D 32x32: col(hid_local) = l&31, row(pair) = (r&3) + 8*(r>>2) + 4*q2
            #pragma unroll
            for (int r = 0; r < 16; ++r) {
                int prow = (r & 3) + 8 * (r >> 2) + 4 * q2;
                float x = d1[r];
                float s = x * __builtin_amdgcn_rcpf(1.f + __expf(-x));   // silu
                my[prow * LSTR + m * 32 + n32] = s;
            }
        }

        // ---- GEMM2: two 16-pair halves via verified 16x16x32 path ----
        #pragma unroll
        for (int hl = 0; hl < 2; ++hl) {
            f32x4 d2 = {b2s, b2s, b2s, b2s};
            #pragma unroll
            for (int kc = 0; kc < 2; ++kc) {
                const float* rp = &my[(hl * 16 + n16) * LSTR + kc * 32 + q4 * 8];
                float4 lo = *(const float4*)rp;
                float4 hi = *(const float4*)(rp + 4);
                F8 a2;
                a2.u[0] = bfpk(lo.x, lo.y); a2.u[1] = bfpk(lo.z, lo.w);
                a2.u[2] = bfpk(hi.x, hi.y); a2.u[3] = bfpk(hi.z, hi.w);
                d2 = __builtin_amdgcn_mfma_f32_16x16x32_bf16(a2.v, B2f[kc].v, d2, 0, 0, 0);
            }
            // D2: col = o = n16 (<8 real), rows = 4 consecutive pairs -> dwordx4
            if (n16 < NH) {
                int p0 = pbase + hl * 16 + q4 * 4;
                int b = p0 >> 16, lo16 = p0 & 65535;
                float4 st; st.x = d2[0]; st.y = d2[1]; st.z = d2[2]; st.w = d2[3];
                *(float4*)(out + (size_t)b * (NH * 65536) + (size_t)n16 * 65536 + lo16) = st;
            }
        }
    }
}

extern "C" void kernel_launch(void* const* d_in, const int* in_sizes, int n_in,
                              void* d_out, int out_size, void* d_ws, size_t ws_size,
                              hipStream_t stream) {
    const float* ff = (const float*)d_in[0];
    const float* W1 = (const float*)d_in[1];
    const float* b1 = (const float*)d_in[2];
    const float* W2 = (const float*)d_in[3];
    const float* b2 = (const float*)d_in[4];
    float* out = (float*)d_out;
    unsigned char* ws = (unsigned char*)d_ws;   // 4864 bytes used

    pack_weights<<<1, 64, 0, stream>>>(W1, b1, W2, b2, ws);
    const int grid = NPAIRS / (32 * GPW * 4);   // 2048 blocks
    relfeat_mfma2<<<grid, BLOCK, 0, stream>>>(ff, ws, out);
}

// Round 7
// 101.735 us; speedup vs baseline: 1.1249x; 1.0305x over previous
//
#include <hip/hip_runtime.h>
#include <hip/hip_bf16.h>

#define NH 8
#define HID 64
#define NPAIRS (16 * 256 * 256)
#define BLOCK 256
#define LROW 72          // bf16 per LDS row (64 + 8 pad) = 144 B, 16B-aligned

typedef __attribute__((ext_vector_type(8))) short bf16x8;
typedef __attribute__((ext_vector_type(4))) float f32x4;
typedef __attribute__((ext_vector_type(16))) float f32x16;

union F8 { bf16x8 v; unsigned u[4]; uint4 q4; };

// f32 pair -> packed bf16 dword (RNE, a in low half) via HW v_cvt_pk_bf16_f32
__device__ inline unsigned pk2(float a, float b) {
    __hip_bfloat162 h = __float22bfloat162_rn(make_float2(a, b));
    unsigned u;
    __builtin_memcpy(&u, &h, 4);
    return u;
}

// ws layout (bytes):
//   0    : B1 frags [m=0,1][lane] x16B — W1 in 32x32x16 B-layout, K row 12 = b1 (bias-as-feature)
//   2048 : B2 frags [kc=0,1][lane] x16B — W2 in 16x16x32 B-layout (HW-verified R4/R5)
//   4096 : b2v [lane] f32 — (lane&15)<8 ? b2[lane&15] : 0
__global__ void pack_weights(const float* __restrict__ W1, const float* __restrict__ b1,
                             const float* __restrict__ W2, const float* __restrict__ b2,
                             unsigned char* __restrict__ ws) {
    int l = threadIdx.x;               // 0..63
    int n32 = l & 31, q2 = l >> 5;
    int n16 = l & 15, q4 = l >> 4;
    unsigned* B1 = (unsigned*)ws;
    unsigned* B2 = (unsigned*)(ws + 2048);
    float* b2v = (float*)(ws + 4096);
    // 32x32x16 B-layout: lane holds B[k = q2*8 + j][n = l&31]; k=12 row carries b1
    for (int m = 0; m < 2; ++m) {
        int h = m * 32 + n32;
        for (int j2 = 0; j2 < 4; ++j2) {
            int k0 = q2 * 8 + 2 * j2, k1 = k0 + 1;
            float v0 = (k0 < 12) ? W1[k0 * HID + h] : (k0 == 12 ? b1[h] : 0.f);
            float v1 = (k1 < 12) ? W1[k1 * HID + h] : 0.f;
            B1[(m * 64 + l) * 4 + j2] = pk2(v0, v1);
        }
    }
    // 16x16x32 B-layout: lane holds B[k = kc*32 + q4*8 + j][n16]
    for (int kc = 0; kc < 2; ++kc)
        for (int j2 = 0; j2 < 4; ++j2) {
            int k0 = kc * 32 + q4 * 8 + 2 * j2;
            float v0 = (n16 < NH) ? W2[k0 * NH + n16] : 0.f;
            float v1 = (n16 < NH) ? W2[(k0 + 1) * NH + n16] : 0.f;
            B2[(kc * 64 + l) * 4 + j2] = pk2(v0, v1);
        }
    b2v[l] = (n16 < NH) ? b2[n16] : 0.f;
}

__global__ __launch_bounds__(BLOCK) void relfeat_mfma3(
    const float* __restrict__ ff, const unsigned char* __restrict__ ws,
    float* __restrict__ out)
{
    __shared__ unsigned short lds[4][32 * LROW];   // 18432 B/block -> 8 blocks/CU
    const int tid = threadIdx.x;
    const int w = tid >> 6, l = tid & 63;
    const int n32 = l & 31, q2 = l >> 5;
    const int n16 = l & 15, q4 = l >> 4;
    unsigned short* my = lds[w];                   // per-wave private, no barriers

    F8 B1f[2], B2f[2];
    B1f[0].q4 = ((const uint4*)ws)[l];
    B1f[1].q4 = ((const uint4*)ws)[64 + l];
    B2f[0].q4 = ((const uint4*)(ws + 2048))[l];
    B2f[1].q4 = ((const uint4*)(ws + 2048))[64 + l];
    const float b2s = ((const float*)(ws + 4096))[l];

    f32x16 z16;
    #pragma unroll
    for (int r = 0; r < 16; ++r) z16[r] = 0.f;

    const int wave_base = (blockIdx.x * 4 + w) * 128;

    #pragma unroll
    for (int it = 0; it < 2; ++it) {
        const int pbase = wave_base + it * 64;

        // ---- each lane computes ITS OWN pair (pbase + l) fully ----
        float4 v = ((const float4*)ff)[pbase + l];
        float rx = v.x, ry = v.y, rvx = v.z, rvy = v.w;
        float dist = sqrtf(rx * rx + ry * ry + 1e-6f);
        float speed_sq = rvx * rvx + rvy * rvy;
        float dot_vp = rvx * rx + rvy * ry;
        float invd = __builtin_amdgcn_rcpf(dist + 1e-6f);
        float inv_dist = __builtin_amdgcn_rcpf(dist + 0.1f);
        float rel_speed = sqrtf(speed_sq + 1e-6f);
        float closing = dot_vp * invd;
        float dir_x = rx * invd, dir_y = ry * invd;
        float zz = -dot_vp * __builtin_amdgcn_rcpf(speed_sq + 1e-6f);
        float ez = __expf(2.f * zz);
        float ttca = 1.f - 2.f * __builtin_amdgcn_rcpf(ez + 1.f);   // tanh(zz)

        unsigned c0 = pk2(rx, ry), c1 = pk2(rvx, rvy);
        unsigned c2 = pk2(dist, inv_dist), c3 = pk2(rel_speed, closing);
        unsigned c4 = pk2(dir_x, dir_y), c5 = pk2(ttca, dot_vp);
        // exchange halves: low lanes get high-lane data and vice versa
        unsigned sw0 = (unsigned)__shfl_xor((int)c0, 32);
        unsigned sw1 = (unsigned)__shfl_xor((int)c1, 32);
        unsigned sw2 = (unsigned)__shfl_xor((int)c2, 32);
        unsigned sw3 = (unsigned)__shfl_xor((int)c3, 32);
        unsigned sw4 = (unsigned)__shfl_xor((int)c4, 32);
        unsigned sw5 = (unsigned)__shfl_xor((int)c5, 32);

        // A1 frags (32x32x16, HW-verified): A[m = l&31][k = q2*8 + j]
        // group X = pairs pbase+0..31, group Y = pairs pbase+32..63
        const bool hi = (q2 != 0);
        F8 frag[2];
        frag[0].u[0] = hi ? sw4 : c0;            // k 8,9  | k 0,1
        frag[0].u[1] = hi ? sw5 : c1;            // k10,11 | k 2,3
        frag[0].u[2] = hi ? 0x00003f80u : c2;    // k12=1 (bias), 13=0 | k 4,5
        frag[0].u[3] = hi ? 0u : c3;             // k14,15=0 | k 6,7
        frag[1].u[0] = hi ? c4 : sw0;
        frag[1].u[1] = hi ? c5 : sw1;
        frag[1].u[2] = hi ? 0x00003f80u : sw2;
        frag[1].u[3] = hi ? 0u : sw3;

        #pragma unroll
        for (int G = 0; G < 2; ++G) {
            const int pg = pbase + G * 32;

            // GEMM1: 2x mfma 32x32x16 (hid halves); silu; bf16 LDS [pair][hid]
            #pragma unroll
            for (int m = 0; m < 2; ++m) {
                f32x16 d1 = __builtin_amdgcn_mfma_f32_32x32x16_bf16(frag[G].v, B1f[m].v, z16, 0, 0, 0);
                // C/D 32x32: col(hid) = l&31 (+32m), row(pair) = (r&3)+8*(r>>2)+4*q2
                #pragma unroll
                for (int r = 0; r < 16; ++r) {
                    int prow = (r & 3) + 8 * (r >> 2) + 4 * q2;
                    float x = d1[r];
                    float s = x * __builtin_amdgcn_rcpf(1.f + __expf(-x));   // silu
                    my[prow * LROW + m * 32 + n32] = (unsigned short)pk2(s, s);
                }
            }

            // GEMM2: A2 frag = one ds_read_b128 of 8 consecutive bf16 hid values
            #pragma unroll
            for (int hl = 0; hl < 2; ++hl) {
                f32x4 d2 = {b2s, b2s, b2s, b2s};
                #pragma unroll
                for (int kc = 0; kc < 2; ++kc) {
                    F8 a2;
                    a2.q4 = *(const uint4*)((const unsigned char*)my
                              + (hl * 16 + n16) * (LROW * 2) + kc * 64 + q4 * 16);
                    d2 = __builtin_amdgcn_mfma_f32_16x16x32_bf16(a2.v, B2f[kc].v, d2, 0, 0, 0);
                }
                // D2: col = o = n16 (<8 real), rows = 4 consecutive pairs -> dwordx4
                if (n16 < NH) {
                    int p0 = pg + hl * 16 + q4 * 4;
                    int b = p0 >> 16, lo16 = p0 & 65535;
                    float4 st; st.x = d2[0]; st.y = d2[1]; st.z = d2[2]; st.w = d2[3];
                    *(float4*)(out + (size_t)b * (NH * 65536) + (size_t)n16 * 65536 + lo16) = st;
                }
            }
        }
    }
}

extern "C" void kernel_launch(void* const* d_in, const int* in_sizes, int n_in,
                              void* d_out, int out_size, void* d_ws, size_t ws_size,
                              hipStream_t stream) {
    const float* ff = (const float*)d_in[0];
    const float* W1 = (const float*)d_in[1];
    const float* b1 = (const float*)d_in[2];
    const float* W2 = (const float*)d_in[3];
    const float* b2 = (const float*)d_in[4];
    float* out = (float*)d_out;
    unsigned char* ws = (unsigned char*)d_ws;   // 4352 bytes used

    pack_weights<<<1, 64, 0, stream>>>(W1, b1, W2, b2, ws);
    const int grid = NPAIRS / (128 * 4);        // 2048 blocks, 4 waves x 128 pairs
    relfeat_mfma3<<<grid, BLOCK, 0, stream>>>(ff, ws, out);
}